// Round 5
// baseline (121.239 us; speedup 1.0000x reference)
//
#include <hip/hip_runtime.h>
#include <climits>

// Problem constants (setup_inputs: B=8, N=20000, G=300, C=80)
#define BB 8
#define NA 20000
#define GG 300
#define NCLS 80
#define KK 4
#define MAXPOS 128
#define T_HIGH 0.7f
#define BLK 1024
#define NWAVE (BLK / 64)
#define ACACHE 1024         // LDS anchor-cache capacity (buckets avg ~250, +49 sigma to overflow)
#define NBW ((NA + 31) / 32)

// Single compiled instance (noinline) so every IoU evaluation is bitwise
// identical (absmax 0.0 in R1-R4) -> `iou == gt_max` lq test is exact.
__device__ __attribute__((noinline)) float iou_cxcywh(
    float acx, float acy, float aw, float ah,
    float bcx, float bcy, float bw, float bh)
{
    float ax0 = acx - 0.5f * aw, ay0 = acy - 0.5f * ah;
    float ax1 = acx + 0.5f * aw, ay1 = acy + 0.5f * ah;
    float bx0 = bcx - 0.5f * bw, by0 = bcy - 0.5f * bh;
    float bx1 = bcx + 0.5f * bw, by1 = bcy + 0.5f * bh;
    float area_a = (ax1 - ax0) * (ay1 - ay0);
    float area_b = (bx1 - bx0) * (by1 - by0);
    float ltx = fmaxf(ax0, bx0), lty = fmaxf(ay0, by0);
    float rbx = fminf(ax1, bx1), rby = fminf(ay1, by1);
    float wx = fmaxf(rbx - ltx, 0.0f), wy = fmaxf(rby - lty, 0.0f);
    float inter = wx * wy;
    return inter / (area_a + area_b - inter);
}

// lex top-4 insert: (value desc, index asc) == lax.top_k order
__device__ __forceinline__ void ins4(float* tv, int* ti_, float iou, int n)
{
    if (iou > tv[3] || (iou == tv[3] && n < ti_[3])) {
        tv[3] = iou; ti_[3] = n;
#pragma unroll
        for (int j = 3; j > 0; --j) {
            bool up = (tv[j] > tv[j-1]) || (tv[j] == tv[j-1] && ti_[j] < ti_[j-1]);
            if (up) {
                float fv = tv[j]; tv[j] = tv[j-1]; tv[j-1] = fv;
                int   ii = ti_[j]; ti_[j] = ti_[j-1]; ti_[j-1] = ii;
            }
        }
    }
}

// merge two sorted-desc top-4 lists -> top-4 of union
__device__ __forceinline__ void merge4(
    const float* av, const int* ai, const float* bv, const int* bi,
    float* ov, int* oi)
{
    int x = 0, y = 0;
#pragma unroll
    for (int k = 0; k < 4; ++k) {
        bool takeA = (av[x] > bv[y]) || (av[x] == bv[y] && ai[x] < bi[y]);
        if (takeA) { ov[k] = av[x]; oi[k] = ai[x]; ++x; }
        else       { ov[k] = bv[y]; oi[k] = bi[y]; ++y; }
    }
}

// ---------------------------------------------------------------------------
// k_main: ONE block per (b, class), 1024 threads. Anchors of class c interact
// only with gts of class c, so everything is intra-block. Single dispatch.
// ---------------------------------------------------------------------------
__global__ __launch_bounds__(1024) void k_main(
    const float* __restrict__ anchors,   // [B,NA,4] cxcywh
    const int*   __restrict__ prompt,    // [B,NA]
    const int*   __restrict__ tlabels,   // [B,G]
    const float* __restrict__ tboxes,    // [B,G,4] cxcywh
    float* __restrict__ out)             // [4][B,G,K] concatenated
{
    int bc = blockIdx.x;
    int b = bc / NCLS, c = bc - b * NCLS;
    int tid = threadIdx.x;
    int lane = tid & 63, wave = tid >> 6;

    __shared__ float4 gbox[GG];              // class gt boxes (ascending g)
    __shared__ int    gidx[GG];              // class gt global indices
    __shared__ float  gmaxv[GG];             // per-gt row max
    __shared__ int    lcount[GG];            // per-gt positive counts
    __shared__ float  gtv[GG * KK];          // per-gt top-4 values
    __shared__ int    gti[GG * KK];          // per-gt top-4 anchor indices
    __shared__ float4 s_abox[ACACHE];        // bucket anchor boxes
    __shared__ int    s_aidx[ACACHE];        // bucket anchor global indices
    __shared__ unsigned short s_aarg[ACACHE];// per-anchor local argmax (cached)
    __shared__ unsigned int s_posbit[NBW];   // positive bitmask (slot- or n-indexed)
    __shared__ int    sd[BLK];               // cold-path scan buffer
    __shared__ int    s_wcnt[NWAVE];
    __shared__ int    s_acnt, s_ptotal;

    // ---- 1. stable ballot-compaction of class gts (ascending g; GG<=BLK) ----
    bool gflag = (tid < GG) && (tlabels[b * GG + tid] == c);
    unsigned long long m = __ballot(gflag);
    if (lane == 0) s_wcnt[wave] = __popcll(m);
    if (tid == 0) { s_acnt = 0; s_ptotal = 0; }
    __syncthreads();
    int G_c = 0;
#pragma unroll
    for (int w = 0; w < NWAVE; ++w) G_c += s_wcnt[w];
    if (G_c == 0) return;   // uniform: no gts of this class -> no outputs owned
    {
        int off = 0;
        for (int w = 0; w < wave; ++w) off += s_wcnt[w];
        off += __popcll(m & ((1ull << lane) - 1));
        if (gflag) {
            gidx[off] = tid;
            gbox[off] = ((const float4*)tboxes)[b * GG + tid];
        }
    }
    for (int i = tid; i < NBW; i += BLK) s_posbit[i] = 0u;
    for (int gi = tid; gi < G_c; gi += BLK) lcount[gi] = 0;
    __syncthreads();

    // ---- 2. collect class anchors into LDS cache (order irrelevant) ----
    const int4*   prow4 = (const int4*)(prompt + (size_t)b * NA);
    const float4* arow  = (const float4*)anchors + (size_t)b * NA;
    for (int q = tid; q < NA / 4; q += BLK) {
        int4 p4 = prow4[q];
        int ps[4] = {p4.x, p4.y, p4.z, p4.w};
#pragma unroll
        for (int u = 0; u < 4; ++u) {
            if (ps[u] == c) {
                int slot = atomicAdd(&s_acnt, 1);
                if (slot < ACACHE) {
                    int j = 4 * q + u;
                    s_aidx[slot] = j;
                    s_abox[slot] = arow[j];
                }
            }
        }
    }
    __syncthreads();
    int A_c = s_acnt;
    bool cached = (A_c <= ACACHE);

    // ---- 3. per-gt lex top-4; gts round-robin over waves, butterfly merge ----
    for (int gi = wave; gi < G_c; gi += NWAVE) {
        float4 gb = gbox[gi];
        float tv[4]  = {-2.0f, -2.0f, -2.0f, -2.0f};   // sentinel < any IoU
        int   ti_[4] = {INT_MAX, INT_MAX, INT_MAX, INT_MAX};
        if (cached) {
            for (int slot = lane; slot < A_c; slot += 64) {
                float4 ab = s_abox[slot];
                float iou = iou_cxcywh(gb.x, gb.y, gb.z, gb.w, ab.x, ab.y, ab.z, ab.w);
                ins4(tv, ti_, iou, s_aidx[slot]);
            }
        } else {  // cold: bucket overflowed LDS cache -> rescan globally
            for (int n = lane; n < NA; n += 64) {
                if (prompt[(size_t)b * NA + n] != c) continue;
                float4 ab = arow[n];
                float iou = iou_cxcywh(gb.x, gb.y, gb.z, gb.w, ab.x, ab.y, ab.z, ab.w);
                ins4(tv, ti_, iou, n);
            }
        }
#pragma unroll
        for (int mask = 1; mask < 64; mask <<= 1) {
            float bv[4], ov[4];
            int   bi[4], oi[4];
#pragma unroll
            for (int j = 0; j < 4; ++j) {
                bv[j] = __shfl_xor(tv[j], mask, 64);
                bi[j] = __shfl_xor(ti_[j], mask, 64);
            }
            merge4(tv, ti_, bv, bi, ov, oi);
#pragma unroll
            for (int j = 0; j < 4; ++j) { tv[j] = ov[j]; ti_[j] = oi[j]; }
        }
        if (lane == 0) {
            gmaxv[gi] = tv[0];
#pragma unroll
            for (int k = 0; k < 4; ++k) { gtv[gi*KK+k] = tv[k]; gti[gi*KK+k] = ti_[k]; }
        }
    }
    __syncthreads();

    // ---- 4. per-anchor: argmax (first occurrence: ascending gi, strict >),
    //         lq (iou == gt row max, exact), pos, per-gt counts ----
    if (cached) {
        for (int slot = tid; slot < A_c; slot += BLK) {
            float4 ab = s_abox[slot];
            float amax = -1.0f; int aarg = 0; bool lq = false;
            for (int gi = 0; gi < G_c; ++gi) {
                float4 gb = gbox[gi];
                float iou = iou_cxcywh(gb.x, gb.y, gb.z, gb.w, ab.x, ab.y, ab.z, ab.w);
                lq = lq || (iou == gmaxv[gi]);
                if (iou > amax) { amax = iou; aarg = gi; }
            }
            s_aarg[slot] = (unsigned short)aarg;
            if (lq || amax >= T_HIGH) {
                atomicOr(&s_posbit[slot >> 5], 1u << (slot & 31));
                atomicAdd(&lcount[aarg], 1);
                atomicAdd(&s_ptotal, 1);
            }
        }
    } else {  // cold: bitmask indexed by global anchor index
        for (int n = tid; n < NA; n += BLK) {
            if (prompt[(size_t)b * NA + n] != c) continue;
            float4 ab = arow[n];
            float amax = -1.0f; int aarg = 0; bool lq = false;
            for (int gi = 0; gi < G_c; ++gi) {
                float4 gb = gbox[gi];
                float iou = iou_cxcywh(gb.x, gb.y, gb.z, gb.w, ab.x, ab.y, ab.z, ab.w);
                lq = lq || (iou == gmaxv[gi]);
                if (iou > amax) { amax = iou; aarg = gi; }
            }
            if (lq || amax >= T_HIGH) {
                atomicOr(&s_posbit[n >> 5], 1u << (n & 31));
                atomicAdd(&lcount[aarg], 1);
                atomicAdd(&s_ptotal, 1);
            }
        }
    }
    __syncthreads();
    int ptotal = s_ptotal;

    // ---- 5. subsample: > MAXPOS positives -> keep first MAXPOS by anchor
    //         index (exact stable argsort-by-(class,idx) rank) ----
    if (ptotal > MAXPOS) {
        for (int gi = tid; gi < G_c; gi += BLK) lcount[gi] = 0;
        __syncthreads();
        if (cached) {
            for (int slot = tid; slot < A_c; slot += BLK) {
                if (!((s_posbit[slot >> 5] >> (slot & 31)) & 1)) continue;
                int n = s_aidx[slot];
                int rank = 0;
                for (int s2 = 0; s2 < A_c; ++s2)
                    if (((s_posbit[s2 >> 5] >> (s2 & 31)) & 1) && s_aidx[s2] < n) ++rank;
                if (rank < MAXPOS) atomicAdd(&lcount[s_aarg[slot]], 1);
            }
        } else {  // cold^2: ordered block scan over the n-indexed bitmask
            int running = 0;
            for (int base = 0; base < NA && running < MAXPOS; base += BLK) {
                int n = base + tid;
                int flag = (n < NA) && ((s_posbit[n >> 5] >> (n & 31)) & 1);
                sd[tid] = flag;
                __syncthreads();
                for (int off = 1; off < BLK; off <<= 1) {
                    int v = (tid >= off) ? sd[tid - off] : 0;
                    __syncthreads();
                    sd[tid] += v;
                    __syncthreads();
                }
                int rank = running + sd[tid] - flag;
                int total = sd[BLK - 1];
                if (flag && rank < MAXPOS) {
                    float4 ab = arow[n];
                    float amax = -1.0f; int aarg = 0;
                    for (int gi = 0; gi < G_c; ++gi) {
                        float4 gb = gbox[gi];
                        float iou = iou_cxcywh(gb.x, gb.y, gb.z, gb.w, ab.x, ab.y, ab.z, ab.w);
                        if (iou > amax) { amax = iou; aarg = gi; }
                    }
                    atomicAdd(&lcount[aarg], 1);
                }
                running += total;
                __syncthreads();
            }
        }
        __syncthreads();
    }

    // ---- 6. outputs for this class's gts: [4][B,G,K] concatenated ----
    const int TOT = BB * GG * KK;
    for (int t = tid; t < G_c * KK; t += BLK) {
        int gi = t >> 2, k = t & 3;
        int gg = gidx[gi];
        int cnt = lcount[gi]; if (cnt > KK) cnt = KK;
        bool svld = (k < cnt);
        int o = (b * GG + gg) * KK + k;
        out[o]           = svld ? (float)gti[t] : -1.0f;   // pr_inds
        out[TOT + o]     = svld ? (float)gg     : -1.0f;   // gt_inds
        out[2*TOT + o]   = svld ? 1.0f : 0.0f;             // slot_valid
        out[3*TOT + o]   = svld ? gtv[t] : 0.0f;           // pos_iou
    }
}

extern "C" void kernel_launch(void* const* d_in, const int* in_sizes, int n_in,
                              void* d_out, int out_size, void* d_ws, size_t ws_size,
                              hipStream_t stream) {
    // inputs: 0 pred_logits_match (unused), 1 pred_boxes (unused),
    //         2 anchors, 3 prompt_inds, 4 tgt_labels, 5 tgt_boxes
    const float* anchors = (const float*)d_in[2];
    const int*   prompt  = (const int*)d_in[3];
    const int*   tlabels = (const int*)d_in[4];
    const float* tboxes  = (const float*)d_in[5];
    float* out = (float*)d_out;

    k_main<<<BB * NCLS, BLK, 0, stream>>>(anchors, prompt, tlabels, tboxes, out);
}

// Round 6
// 103.545 us; speedup vs baseline: 1.1709x; 1.1709x over previous
//
#include <hip/hip_runtime.h>
#include <climits>

// Problem constants (setup_inputs: B=8, N=20000, G=300, C=80)
#define BB 8
#define NA 20000
#define GG 300
#define NCLS 80
#define KK 4
#define MAXPOS 128
#define T_HIGH 0.7f
#define BLK 512
#define NWAVE (BLK / 64)
#define ACACHE 512          // LDS anchor-cache (bucket ~250 avg, +16 sigma to overflow; exact cold path kept)
#define NBW ((NA + 31) / 32)

// Inlined everywhere, but contraction is OFF so every instance compiles the
// exact same single-rounded IEEE op sequence (== numpy's plain mul/add/sub
// order). Keeps `iou == gt_max` bitwise-exact across phases AND matches the
// reference selections exactly (absmax 0.0 in R1-R5 with the noinline
// variant; contract(off) preserves that without the call overhead).
__device__ __forceinline__ float iou_cxcywh(
    float acx, float acy, float aw, float ah,
    float bcx, float bcy, float bw, float bh)
{
#pragma clang fp contract(off)
    float ax0 = acx - 0.5f * aw, ay0 = acy - 0.5f * ah;
    float ax1 = acx + 0.5f * aw, ay1 = acy + 0.5f * ah;
    float bx0 = bcx - 0.5f * bw, by0 = bcy - 0.5f * bh;
    float bx1 = bcx + 0.5f * bw, by1 = bcy + 0.5f * bh;
    float area_a = (ax1 - ax0) * (ay1 - ay0);
    float area_b = (bx1 - bx0) * (by1 - by0);
    float ltx = fmaxf(ax0, bx0), lty = fmaxf(ay0, by0);
    float rbx = fminf(ax1, bx1), rby = fminf(ay1, by1);
    float wx = fmaxf(rbx - ltx, 0.0f), wy = fmaxf(rby - lty, 0.0f);
    float inter = wx * wy;
    return inter / ((area_a + area_b) - inter);
}

// lex top-4 insert: (value desc, index asc) == lax.top_k order
__device__ __forceinline__ void ins4(float* tv, int* ti_, float iou, int n)
{
    if (iou > tv[3] || (iou == tv[3] && n < ti_[3])) {
        tv[3] = iou; ti_[3] = n;
#pragma unroll
        for (int j = 3; j > 0; --j) {
            bool up = (tv[j] > tv[j-1]) || (tv[j] == tv[j-1] && ti_[j] < ti_[j-1]);
            if (up) {
                float fv = tv[j]; tv[j] = tv[j-1]; tv[j-1] = fv;
                int   ii = ti_[j]; ti_[j] = ti_[j-1]; ti_[j-1] = ii;
            }
        }
    }
}

// merge two sorted-desc top-4 lists -> top-4 of union
__device__ __forceinline__ void merge4(
    const float* av, const int* ai, const float* bv, const int* bi,
    float* ov, int* oi)
{
    int x = 0, y = 0;
#pragma unroll
    for (int k = 0; k < 4; ++k) {
        bool takeA = (av[x] > bv[y]) || (av[x] == bv[y] && ai[x] < bi[y]);
        if (takeA) { ov[k] = av[x]; oi[k] = ai[x]; ++x; }
        else       { ov[k] = bv[y]; oi[k] = bi[y]; ++y; }
    }
}

// ---------------------------------------------------------------------------
// k_main: ONE block per (b, class), 512 threads, ~33 KB LDS -> 4 blocks/CU,
// all 640 blocks co-resident (single scheduling round). Anchors of class c
// interact only with gts of class c, so everything is intra-block.
// ---------------------------------------------------------------------------
__global__ __launch_bounds__(BLK, 8) void k_main(
    const float* __restrict__ anchors,   // [B,NA,4] cxcywh
    const int*   __restrict__ prompt,    // [B,NA]
    const int*   __restrict__ tlabels,   // [B,G]
    const float* __restrict__ tboxes,    // [B,G,4] cxcywh
    float* __restrict__ out)             // [4][B,G,K] concatenated
{
    int bc = blockIdx.x;
    int b = bc / NCLS, c = bc - b * NCLS;
    int tid = threadIdx.x;
    int lane = tid & 63, wave = tid >> 6;

    __shared__ float4 gbox[GG];              // class gt boxes (ascending g)
    __shared__ int    gidx[GG];              // class gt global indices
    __shared__ float  gmaxv[GG];             // per-gt row max
    __shared__ int    lcount[GG];            // per-gt positive counts
    __shared__ float  gtv[GG * KK];          // per-gt top-4 values
    __shared__ int    gti[GG * KK];          // per-gt top-4 anchor indices
    __shared__ float4 s_abox[ACACHE];        // bucket anchor boxes
    __shared__ int    s_aidx[ACACHE];        // bucket anchor global indices
    __shared__ union {                       // overlay: s_aarg used only on
        unsigned short aarg[ACACHE];         //   cached path, sd only on cold
        int            sd[BLK];
    } u;
    __shared__ unsigned int s_posbit[NBW];   // positive bitmask (slot- or n-indexed)
    __shared__ int    s_wcnt[NWAVE];
    __shared__ int    s_acnt, s_ptotal;

    // ---- 1. stable ballot-compaction of class gts (ascending g; GG<=BLK) ----
    bool gflag = (tid < GG) && (tlabels[b * GG + tid] == c);
    unsigned long long m = __ballot(gflag);
    if (lane == 0) s_wcnt[wave] = __popcll(m);
    if (tid == 0) { s_acnt = 0; s_ptotal = 0; }
    __syncthreads();
    int G_c = 0;
#pragma unroll
    for (int w = 0; w < NWAVE; ++w) G_c += s_wcnt[w];
    if (G_c == 0) return;   // uniform exit: no gts of this class
    {
        int off = 0;
        for (int w = 0; w < wave; ++w) off += s_wcnt[w];
        off += __popcll(m & ((1ull << lane) - 1));
        if (gflag) {
            gidx[off] = tid;
            gbox[off] = ((const float4*)tboxes)[b * GG + tid];
        }
    }
    for (int i = tid; i < NBW; i += BLK) s_posbit[i] = 0u;
    for (int gi = tid; gi < G_c; gi += BLK) lcount[gi] = 0;
    __syncthreads();

    // ---- 2. collect class anchors into LDS cache (order irrelevant) ----
    const int4*   prow4 = (const int4*)(prompt + (size_t)b * NA);
    const float4* arow  = (const float4*)anchors + (size_t)b * NA;
    for (int q = tid; q < NA / 4; q += BLK) {
        int4 p4 = prow4[q];
        int ps[4] = {p4.x, p4.y, p4.z, p4.w};
#pragma unroll
        for (int uu = 0; uu < 4; ++uu) {
            if (ps[uu] == c) {
                int slot = atomicAdd(&s_acnt, 1);
                if (slot < ACACHE) {
                    int j = 4 * q + uu;
                    s_aidx[slot] = j;
                    s_abox[slot] = arow[j];
                }
            }
        }
    }
    __syncthreads();
    int A_c = s_acnt;
    bool cached = (A_c <= ACACHE);

    // ---- 3. per-gt lex top-4; gts round-robin over waves, butterfly merge ----
    for (int gi = wave; gi < G_c; gi += NWAVE) {
        float4 gb = gbox[gi];
        float tv[4]  = {-2.0f, -2.0f, -2.0f, -2.0f};   // sentinel < any IoU
        int   ti_[4] = {INT_MAX, INT_MAX, INT_MAX, INT_MAX};
        if (cached) {
            for (int slot = lane; slot < A_c; slot += 64) {
                float4 ab = s_abox[slot];
                float iou = iou_cxcywh(gb.x, gb.y, gb.z, gb.w, ab.x, ab.y, ab.z, ab.w);
                ins4(tv, ti_, iou, s_aidx[slot]);
            }
        } else {  // cold: bucket overflowed LDS cache -> rescan globally
            for (int n = lane; n < NA; n += 64) {
                if (prompt[(size_t)b * NA + n] != c) continue;
                float4 ab = arow[n];
                float iou = iou_cxcywh(gb.x, gb.y, gb.z, gb.w, ab.x, ab.y, ab.z, ab.w);
                ins4(tv, ti_, iou, n);
            }
        }
#pragma unroll
        for (int mask = 1; mask < 64; mask <<= 1) {
            float bv[4], ov[4];
            int   bi[4], oi[4];
#pragma unroll
            for (int j = 0; j < 4; ++j) {
                bv[j] = __shfl_xor(tv[j], mask, 64);
                bi[j] = __shfl_xor(ti_[j], mask, 64);
            }
            merge4(tv, ti_, bv, bi, ov, oi);
#pragma unroll
            for (int j = 0; j < 4; ++j) { tv[j] = ov[j]; ti_[j] = oi[j]; }
        }
        if (lane == 0) {
            gmaxv[gi] = tv[0];
#pragma unroll
            for (int k = 0; k < 4; ++k) { gtv[gi*KK+k] = tv[k]; gti[gi*KK+k] = ti_[k]; }
        }
    }
    __syncthreads();

    // ---- 4. per-anchor: argmax (first occurrence: ascending gi, strict >),
    //         lq (iou == gt row max, exact), pos, per-gt counts ----
    if (cached) {
        for (int slot = tid; slot < A_c; slot += BLK) {
            float4 ab = s_abox[slot];
            float amax = -1.0f; int aarg = 0; bool lq = false;
            for (int gi = 0; gi < G_c; ++gi) {
                float4 gb = gbox[gi];
                float iou = iou_cxcywh(gb.x, gb.y, gb.z, gb.w, ab.x, ab.y, ab.z, ab.w);
                lq = lq || (iou == gmaxv[gi]);
                if (iou > amax) { amax = iou; aarg = gi; }
            }
            u.aarg[slot] = (unsigned short)aarg;
            if (lq || amax >= T_HIGH) {
                atomicOr(&s_posbit[slot >> 5], 1u << (slot & 31));
                atomicAdd(&lcount[aarg], 1);
                atomicAdd(&s_ptotal, 1);
            }
        }
    } else {  // cold: bitmask indexed by global anchor index
        for (int n = tid; n < NA; n += BLK) {
            if (prompt[(size_t)b * NA + n] != c) continue;
            float4 ab = arow[n];
            float amax = -1.0f; int aarg = 0; bool lq = false;
            for (int gi = 0; gi < G_c; ++gi) {
                float4 gb = gbox[gi];
                float iou = iou_cxcywh(gb.x, gb.y, gb.z, gb.w, ab.x, ab.y, ab.z, ab.w);
                lq = lq || (iou == gmaxv[gi]);
                if (iou > amax) { amax = iou; aarg = gi; }
            }
            if (lq || amax >= T_HIGH) {
                atomicOr(&s_posbit[n >> 5], 1u << (n & 31));
                atomicAdd(&lcount[aarg], 1);
                atomicAdd(&s_ptotal, 1);
            }
        }
    }
    __syncthreads();
    int ptotal = s_ptotal;

    // ---- 5. subsample: > MAXPOS positives -> keep first MAXPOS by anchor
    //         index (exact stable argsort-by-(class,idx) rank) ----
    if (ptotal > MAXPOS) {
        for (int gi = tid; gi < G_c; gi += BLK) lcount[gi] = 0;
        __syncthreads();
        if (cached) {
            for (int slot = tid; slot < A_c; slot += BLK) {
                if (!((s_posbit[slot >> 5] >> (slot & 31)) & 1)) continue;
                int n = s_aidx[slot];
                int rank = 0;
                for (int s2 = 0; s2 < A_c; ++s2)
                    if (((s_posbit[s2 >> 5] >> (s2 & 31)) & 1) && s_aidx[s2] < n) ++rank;
                if (rank < MAXPOS) atomicAdd(&lcount[u.aarg[slot]], 1);
            }
        } else {  // cold^2: ordered block scan over the n-indexed bitmask
            int running = 0;
            for (int base = 0; base < NA && running < MAXPOS; base += BLK) {
                int n = base + tid;
                int flag = (n < NA) && ((s_posbit[n >> 5] >> (n & 31)) & 1);
                u.sd[tid] = flag;
                __syncthreads();
                for (int off = 1; off < BLK; off <<= 1) {
                    int v = (tid >= off) ? u.sd[tid - off] : 0;
                    __syncthreads();
                    u.sd[tid] += v;
                    __syncthreads();
                }
                int rank = running + u.sd[tid] - flag;
                int total = u.sd[BLK - 1];
                if (flag && rank < MAXPOS) {
                    float4 ab = arow[n];
                    float amax = -1.0f; int aarg = 0;
                    for (int gi = 0; gi < G_c; ++gi) {
                        float4 gb = gbox[gi];
                        float iou = iou_cxcywh(gb.x, gb.y, gb.z, gb.w, ab.x, ab.y, ab.z, ab.w);
                        if (iou > amax) { amax = iou; aarg = gi; }
                    }
                    atomicAdd(&lcount[aarg], 1);
                }
                running += total;
                __syncthreads();
            }
        }
        __syncthreads();
    }

    // ---- 6. outputs for this class's gts: [4][B,G,K] concatenated ----
    const int TOT = BB * GG * KK;
    for (int t = tid; t < G_c * KK; t += BLK) {
        int gi = t >> 2, k = t & 3;
        int gg = gidx[gi];
        int cnt = lcount[gi]; if (cnt > KK) cnt = KK;
        bool svld = (k < cnt);
        int o = (b * GG + gg) * KK + k;
        out[o]           = svld ? (float)gti[t] : -1.0f;   // pr_inds
        out[TOT + o]     = svld ? (float)gg     : -1.0f;   // gt_inds
        out[2*TOT + o]   = svld ? 1.0f : 0.0f;             // slot_valid
        out[3*TOT + o]   = svld ? gtv[t] : 0.0f;           // pos_iou
    }
}

extern "C" void kernel_launch(void* const* d_in, const int* in_sizes, int n_in,
                              void* d_out, int out_size, void* d_ws, size_t ws_size,
                              hipStream_t stream) {
    // inputs: 0 pred_logits_match (unused), 1 pred_boxes (unused),
    //         2 anchors, 3 prompt_inds, 4 tgt_labels, 5 tgt_boxes
    const float* anchors = (const float*)d_in[2];
    const int*   prompt  = (const int*)d_in[3];
    const int*   tlabels = (const int*)d_in[4];
    const float* tboxes  = (const float*)d_in[5];
    float* out = (float*)d_out;

    k_main<<<BB * NCLS, BLK, 0, stream>>>(anchors, prompt, tlabels, tboxes, out);
}

// Round 7
// 92.845 us; speedup vs baseline: 1.3058x; 1.1152x over previous
//
#include <hip/hip_runtime.h>
#include <climits>

// Problem constants (setup_inputs: B=8, N=20000, G=300, C=80)
#define BB 8
#define NA 20000
#define GG 300
#define NCLS 80
#define KK 4
#define MAXPOS 128
#define T_HIGH 0.7f
#define BLK 512
#define NWAVE (BLK / 64)
#define ACACHE 512          // LDS anchor-cache (bucket ~250 avg; exact cold path kept)
#define NBW ((NA + 31) / 32)

// Inlined everywhere with contraction OFF: every instance compiles the same
// single-rounded IEEE op sequence (== numpy). Keeps `iou == gt_max` exact
// across phases (absmax 0.0 since R1).
__device__ __forceinline__ float iou_cxcywh(
    float acx, float acy, float aw, float ah,
    float bcx, float bcy, float bw, float bh)
{
#pragma clang fp contract(off)
    float ax0 = acx - 0.5f * aw, ay0 = acy - 0.5f * ah;
    float ax1 = acx + 0.5f * aw, ay1 = acy + 0.5f * ah;
    float bx0 = bcx - 0.5f * bw, by0 = bcy - 0.5f * bh;
    float bx1 = bcx + 0.5f * bw, by1 = bcy + 0.5f * bh;
    float area_a = (ax1 - ax0) * (ay1 - ay0);
    float area_b = (bx1 - bx0) * (by1 - by0);
    float ltx = fmaxf(ax0, bx0), lty = fmaxf(ay0, by0);
    float rbx = fminf(ax1, bx1), rby = fminf(ay1, by1);
    float wx = fmaxf(rbx - ltx, 0.0f), wy = fmaxf(rby - lty, 0.0f);
    float inter = wx * wy;
    return inter / ((area_a + area_b) - inter);
}

// Lex compare-exchange on (value desc, index asc) == lax.top_k order.
// STATIC operands only -> everything stays in VGPRs (no scratch).
#define CE(va, ia, vb, ib) do {                                   \
    bool _sw = ((vb) > (va)) || ((vb) == (va) && (ib) < (ia));    \
    float _fv = _sw ? (va) : (vb); (va) = _sw ? (vb) : (va); (vb) = _fv; \
    int   _fi = _sw ? (ia) : (ib); (ia) = _sw ? (ib) : (ia); (ib) = _fi; \
} while (0)

// ---------------------------------------------------------------------------
// k_main: ONE block per (b, class), 512 threads. Anchors of class c interact
// only with gts of class c -> everything intra-block, single dispatch.
// ---------------------------------------------------------------------------
__global__ __launch_bounds__(BLK, 8) void k_main(
    const float* __restrict__ anchors,   // [B,NA,4] cxcywh
    const int*   __restrict__ prompt,    // [B,NA]
    const int*   __restrict__ tlabels,   // [B,G]
    const float* __restrict__ tboxes,    // [B,G,4] cxcywh
    float* __restrict__ out)             // [4][B,G,K] concatenated
{
    int bc = blockIdx.x;
    int b = bc / NCLS, c = bc - b * NCLS;
    int tid = threadIdx.x;
    int lane = tid & 63, wave = tid >> 6;

    __shared__ float4 gbox[GG];              // class gt boxes (ascending g)
    __shared__ int    gidx[GG];              // class gt global indices
    __shared__ float  gmaxv[GG];             // per-gt row max
    __shared__ int    lcount[GG];            // per-gt positive counts
    __shared__ float  gtv[GG * KK];          // per-gt top-4 values
    __shared__ int    gti[GG * KK];          // per-gt top-4 anchor indices
    __shared__ float4 s_abox[ACACHE];        // bucket anchor boxes
    __shared__ int    s_aidx[ACACHE];        // bucket anchor global indices
    __shared__ union {                       // aarg: cached path only; sd: cold only
        unsigned short aarg[ACACHE];
        int            sd[BLK];
    } u;
    __shared__ unsigned int s_posbit[NBW];   // positive bitmask (slot- or n-indexed)
    __shared__ int    s_wcnt[NWAVE];
    __shared__ int    s_acnt, s_ptotal;

    // ---- 1. stable ballot-compaction of class gts (ascending g; GG<=BLK) ----
    bool gflag = (tid < GG) && (tlabels[b * GG + tid] == c);
    unsigned long long m = __ballot(gflag);
    if (lane == 0) s_wcnt[wave] = __popcll(m);
    if (tid == 0) { s_acnt = 0; s_ptotal = 0; }
    __syncthreads();
    int G_c = 0;
#pragma unroll
    for (int w = 0; w < NWAVE; ++w) G_c += s_wcnt[w];
    if (G_c == 0) return;   // uniform exit: no gts of this class
    {
        int off = 0;
        for (int w = 0; w < wave; ++w) off += s_wcnt[w];
        off += __popcll(m & ((1ull << lane) - 1));
        if (gflag) {
            gidx[off] = tid;
            gbox[off] = ((const float4*)tboxes)[b * GG + tid];
        }
    }
    for (int i = tid; i < NBW; i += BLK) s_posbit[i] = 0u;
    for (int gi = tid; gi < G_c; gi += BLK) lcount[gi] = 0;
    __syncthreads();

    // ---- 2. collect class anchors into LDS cache (order irrelevant);
    //         wave-aggregated slot allocation (one atomic per wave) ----
    const int4*   prow4 = (const int4*)(prompt + (size_t)b * NA);
    const float4* arow  = (const float4*)anchors + (size_t)b * NA;
    for (int q = tid; q < NA / 4; q += BLK) {
        int4 p4 = prow4[q];
        int ps[4] = {p4.x, p4.y, p4.z, p4.w};
#pragma unroll
        for (int uu = 0; uu < 4; ++uu) {
            bool f = (ps[uu] == c);
            unsigned long long wm = __ballot(f);
            int cnt = __popcll(wm);
            if (cnt) {
                int leader = __ffsll((unsigned long long)wm) - 1;
                int base = 0;
                if (lane == leader) base = atomicAdd(&s_acnt, cnt);
                base = __shfl(base, leader, 64);
                if (f) {
                    int slot = base + __popcll(wm & ((1ull << lane) - 1));
                    if (slot < ACACHE) {
                        int j = 4 * q + uu;
                        s_aidx[slot] = j;
                        s_abox[slot] = arow[j];
                    }
                }
            }
        }
    }
    __syncthreads();
    int A_c = s_acnt;
    bool cached = (A_c <= ACACHE);

    // ---- 3. per-gt lex top-4; gts round-robin over waves; all state in
    //         scalar VGPRs; butterfly merge via static bitonic network ----
    for (int gi = wave; gi < G_c; gi += NWAVE) {
        float4 gb = gbox[gi];
        float v0 = -2.0f, v1 = -2.0f, v2 = -2.0f, v3 = -2.0f;  // sentinel < any IoU
        int   j0 = INT_MAX, j1 = INT_MAX, j2 = INT_MAX, j3 = INT_MAX;
        if (cached) {
            for (int slot = lane; slot < A_c; slot += 64) {
                float4 ab = s_abox[slot];
                int n = s_aidx[slot];
                float iou = iou_cxcywh(gb.x, gb.y, gb.z, gb.w, ab.x, ab.y, ab.z, ab.w);
                if (iou > v3 || (iou == v3 && n < j3)) {
                    v3 = iou; j3 = n;
                    CE(v2, j2, v3, j3); CE(v1, j1, v2, j2); CE(v0, j0, v1, j1);
                }
            }
        } else {  // cold: bucket overflowed LDS cache -> rescan globally
            for (int n = lane; n < NA; n += 64) {
                if (prompt[(size_t)b * NA + n] != c) continue;
                float4 ab = arow[n];
                float iou = iou_cxcywh(gb.x, gb.y, gb.z, gb.w, ab.x, ab.y, ab.z, ab.w);
                if (iou > v3 || (iou == v3 && n < j3)) {
                    v3 = iou; j3 = n;
                    CE(v2, j2, v3, j3); CE(v1, j1, v2, j2); CE(v0, j0, v1, j1);
                }
            }
        }
        // butterfly: both lists sorted desc; [v0..v3, w3..w0] is bitonic.
#pragma unroll
        for (int mask = 1; mask < 64; mask <<= 1) {
            float w0 = __shfl_xor(v0, mask, 64), w1 = __shfl_xor(v1, mask, 64);
            float w2 = __shfl_xor(v2, mask, 64), w3 = __shfl_xor(v3, mask, 64);
            int   k0 = __shfl_xor(j0, mask, 64), k1 = __shfl_xor(j1, mask, 64);
            int   k2 = __shfl_xor(j2, mask, 64), k3 = __shfl_xor(j3, mask, 64);
            CE(v0, j0, w3, k3); CE(v1, j1, w2, k2);      // stage 1: top half
            CE(v2, j2, w1, k1); CE(v3, j3, w0, k0);
            CE(v0, j0, v2, j2); CE(v1, j1, v3, j3);      // bitonic-4 cleanup
            CE(v0, j0, v1, j1); CE(v2, j2, v3, j3);
        }
        if (lane == 0) {
            gmaxv[gi] = v0;
            gtv[gi*KK+0] = v0; gti[gi*KK+0] = j0;
            gtv[gi*KK+1] = v1; gti[gi*KK+1] = j1;
            gtv[gi*KK+2] = v2; gti[gi*KK+2] = j2;
            gtv[gi*KK+3] = v3; gti[gi*KK+3] = j3;
        }
    }
    __syncthreads();

    // ---- 4. per-anchor: argmax (first occurrence: ascending gi, strict >),
    //         lq (iou == gt row max, exact), pos, per-gt counts ----
    if (cached) {
        for (int slot = tid; slot < A_c; slot += BLK) {
            float4 ab = s_abox[slot];
            float amax = -1.0f; int aarg = 0; bool lq = false;
            for (int gi = 0; gi < G_c; ++gi) {
                float4 gb = gbox[gi];
                float iou = iou_cxcywh(gb.x, gb.y, gb.z, gb.w, ab.x, ab.y, ab.z, ab.w);
                lq = lq || (iou == gmaxv[gi]);
                if (iou > amax) { amax = iou; aarg = gi; }
            }
            u.aarg[slot] = (unsigned short)aarg;
            if (lq || amax >= T_HIGH) {
                atomicOr(&s_posbit[slot >> 5], 1u << (slot & 31));
                atomicAdd(&lcount[aarg], 1);
                atomicAdd(&s_ptotal, 1);
            }
        }
    } else {  // cold: bitmask indexed by global anchor index
        for (int n = tid; n < NA; n += BLK) {
            if (prompt[(size_t)b * NA + n] != c) continue;
            float4 ab = arow[n];
            float amax = -1.0f; int aarg = 0; bool lq = false;
            for (int gi = 0; gi < G_c; ++gi) {
                float4 gb = gbox[gi];
                float iou = iou_cxcywh(gb.x, gb.y, gb.z, gb.w, ab.x, ab.y, ab.z, ab.w);
                lq = lq || (iou == gmaxv[gi]);
                if (iou > amax) { amax = iou; aarg = gi; }
            }
            if (lq || amax >= T_HIGH) {
                atomicOr(&s_posbit[n >> 5], 1u << (n & 31));
                atomicAdd(&lcount[aarg], 1);
                atomicAdd(&s_ptotal, 1);
            }
        }
    }
    __syncthreads();
    int ptotal = s_ptotal;

    // ---- 5. subsample: > MAXPOS positives -> keep first MAXPOS by anchor
    //         index (exact stable argsort-by-(class,idx) rank) ----
    if (ptotal > MAXPOS) {
        for (int gi = tid; gi < G_c; gi += BLK) lcount[gi] = 0;
        __syncthreads();
        if (cached) {
            for (int slot = tid; slot < A_c; slot += BLK) {
                if (!((s_posbit[slot >> 5] >> (slot & 31)) & 1)) continue;
                int n = s_aidx[slot];
                int rank = 0;
                for (int s2 = 0; s2 < A_c; ++s2)
                    if (((s_posbit[s2 >> 5] >> (s2 & 31)) & 1) && s_aidx[s2] < n) ++rank;
                if (rank < MAXPOS) atomicAdd(&lcount[u.aarg[slot]], 1);
            }
        } else {  // cold^2: ordered block scan over the n-indexed bitmask
            int running = 0;
            for (int base = 0; base < NA && running < MAXPOS; base += BLK) {
                int n = base + tid;
                int flag = (n < NA) && ((s_posbit[n >> 5] >> (n & 31)) & 1);
                u.sd[tid] = flag;
                __syncthreads();
                for (int off = 1; off < BLK; off <<= 1) {
                    int v = (tid >= off) ? u.sd[tid - off] : 0;
                    __syncthreads();
                    u.sd[tid] += v;
                    __syncthreads();
                }
                int rank = running + u.sd[tid] - flag;
                int total = u.sd[BLK - 1];
                if (flag && rank < MAXPOS) {
                    float4 ab = arow[n];
                    float amax = -1.0f; int aarg = 0;
                    for (int gi = 0; gi < G_c; ++gi) {
                        float4 gb = gbox[gi];
                        float iou = iou_cxcywh(gb.x, gb.y, gb.z, gb.w, ab.x, ab.y, ab.z, ab.w);
                        if (iou > amax) { amax = iou; aarg = gi; }
                    }
                    atomicAdd(&lcount[aarg], 1);
                }
                running += total;
                __syncthreads();
            }
        }
        __syncthreads();
    }

    // ---- 6. outputs for this class's gts: [4][B,G,K] concatenated ----
    const int TOT = BB * GG * KK;
    for (int t = tid; t < G_c * KK; t += BLK) {
        int gi = t >> 2, k = t & 3;
        int gg = gidx[gi];
        int cnt = lcount[gi]; if (cnt > KK) cnt = KK;
        bool svld = (k < cnt);
        int o = (b * GG + gg) * KK + k;
        out[o]           = svld ? (float)gti[t] : -1.0f;   // pr_inds
        out[TOT + o]     = svld ? (float)gg     : -1.0f;   // gt_inds
        out[2*TOT + o]   = svld ? 1.0f : 0.0f;             // slot_valid
        out[3*TOT + o]   = svld ? gtv[t] : 0.0f;           // pos_iou
    }
}

extern "C" void kernel_launch(void* const* d_in, const int* in_sizes, int n_in,
                              void* d_out, int out_size, void* d_ws, size_t ws_size,
                              hipStream_t stream) {
    // inputs: 0 pred_logits_match (unused), 1 pred_boxes (unused),
    //         2 anchors, 3 prompt_inds, 4 tgt_labels, 5 tgt_boxes
    const float* anchors = (const float*)d_in[2];
    const int*   prompt  = (const int*)d_in[3];
    const int*   tlabels = (const int*)d_in[4];
    const float* tboxes  = (const float*)d_in[5];
    float* out = (float*)d_out;

    k_main<<<BB * NCLS, BLK, 0, stream>>>(anchors, prompt, tlabels, tboxes, out);
}

// Round 9
// 89.575 us; speedup vs baseline: 1.3535x; 1.0365x over previous
//
#include <hip/hip_runtime.h>
#include <climits>

// Problem constants (setup_inputs: B=8, N=20000, G=300, C=80)
#define BB 8
#define NA 20000
#define GG 300
#define NCLS 80
#define KK 4
#define MAXPOS 128
#define T_HIGH 0.7f
#define BLK 512
#define NWAVE (BLK / 64)
#define ACACHE 512          // LDS anchor-cache (bucket ~250 avg; exact cold path kept)
#define NBW ((NA + 31) / 32)
#define NQ (NA / 4)         // 5000 int4 packets per image

// Inlined everywhere with contraction OFF: every instance compiles the same
// single-rounded IEEE op sequence (== numpy). Keeps `iou == gt_max` exact
// across phases (absmax 0.0 in R1-R7).
__device__ __forceinline__ float iou_cxcywh(
    float acx, float acy, float aw, float ah,
    float bcx, float bcy, float bw, float bh)
{
#pragma clang fp contract(off)
    float ax0 = acx - 0.5f * aw, ay0 = acy - 0.5f * ah;
    float ax1 = acx + 0.5f * aw, ay1 = acy + 0.5f * ah;
    float bx0 = bcx - 0.5f * bw, by0 = bcy - 0.5f * bh;
    float bx1 = bcx + 0.5f * bw, by1 = bcy + 0.5f * bh;
    float area_a = (ax1 - ax0) * (ay1 - ay0);
    float area_b = (bx1 - bx0) * (by1 - by0);
    float ltx = fmaxf(ax0, bx0), lty = fmaxf(ay0, by0);
    float rbx = fminf(ax1, bx1), rby = fminf(ay1, by1);
    float wx = fmaxf(rbx - ltx, 0.0f), wy = fmaxf(rby - lty, 0.0f);
    float inter = wx * wy;
    return inter / ((area_a + area_b) - inter);
}

// Lex compare-exchange on (value desc, index asc) == lax.top_k order.
// STATIC operands only -> state stays in VGPRs (no scratch).
#define CE(va, ia, vb, ib) do {                                   \
    bool _sw = ((vb) > (va)) || ((vb) == (va) && (ib) < (ia));    \
    float _fv = _sw ? (va) : (vb); (va) = _sw ? (vb) : (va); (vb) = _fv; \
    int   _fi = _sw ? (ia) : (ib); (ia) = _sw ? (ib) : (ia); (ib) = _fi; \
} while (0)

// ---------------------------------------------------------------------------
// k_main: ONE block per (b, class), 512 threads. Anchors of class c interact
// only with gts of class c -> everything intra-block, single dispatch.
// ---------------------------------------------------------------------------
__global__ __launch_bounds__(BLK, 8) void k_main(
    const float* __restrict__ anchors,   // [B,NA,4] cxcywh
    const int*   __restrict__ prompt,    // [B,NA]
    const int*   __restrict__ tlabels,   // [B,G]
    const float* __restrict__ tboxes,    // [B,G,4] cxcywh
    float* __restrict__ out)             // [4][B,G,K] concatenated
{
    int bc = blockIdx.x;
    int b = bc / NCLS, c = bc - b * NCLS;
    int tid = threadIdx.x;
    int lane = tid & 63, wave = tid >> 6;

    __shared__ float4 gbox[GG];              // class gt boxes (ascending g)
    __shared__ int    gidx[GG];              // class gt global indices
    __shared__ float  gmaxv[GG];             // per-gt row max
    __shared__ int    lcount[GG];            // per-gt positive counts
    __shared__ float  gtv[GG * KK];          // per-gt top-4 values
    __shared__ int    gti[GG * KK];          // per-gt top-4 anchor indices
    __shared__ float4 s_abox[ACACHE];        // bucket anchor boxes
    __shared__ int    s_aidx[ACACHE];        // bucket anchor global indices
    __shared__ union {                       // aarg: cached path only; sd: cold only
        unsigned short aarg[ACACHE];
        int            sd[BLK];
    } u;
    __shared__ unsigned int s_posbit[NBW];   // positive bitmask (slot- or n-indexed)
    __shared__ int    s_wcnt[NWAVE];
    __shared__ int    s_acnt, s_ptotal;

    // ---- 1. stable ballot-compaction of class gts (ascending g; GG<=BLK) ----
    bool gflag = (tid < GG) && (tlabels[b * GG + tid] == c);
    unsigned long long m = __ballot(gflag);
    if (lane == 0) s_wcnt[wave] = __popcll(m);
    if (tid == 0) { s_acnt = 0; s_ptotal = 0; }
    __syncthreads();
    int G_c = 0;
#pragma unroll
    for (int w = 0; w < NWAVE; ++w) G_c += s_wcnt[w];
    if (G_c == 0) return;   // uniform exit: no gts of this class
    {
        int off = 0;
        for (int w = 0; w < wave; ++w) off += s_wcnt[w];
        off += __popcll(m & ((1ull << lane) - 1));
        if (gflag) {
            gidx[off] = tid;
            gbox[off] = ((const float4*)tboxes)[b * GG + tid];
        }
    }
    for (int i = tid; i < NBW; i += BLK) s_posbit[i] = 0u;
    for (int gi = tid; gi < G_c; gi += BLK) lcount[gi] = 0;
    __syncthreads();

    // ---- 2. collect class anchors into LDS cache (order irrelevant).
    //  UNIFORM trip count (q0 uniform, q=q0+tid may be OOB with flags=false)
    //  so ALL 64 lanes execute every shuffle — R8's partial-wave scan bug
    //  (inactive-lane shfl reads) is gone. One wave inclusive-scan per
    //  iteration; gather loads issued before the scan to overlap L2 latency. ----
    const int4*   prow4 = (const int4*)(prompt + (size_t)b * NA);
    const float4* arow  = (const float4*)anchors + (size_t)b * NA;
    for (int q0 = 0; q0 < NQ; q0 += BLK) {
        int q = q0 + tid;
        bool inb = (q < NQ);
        bool f0 = false, f1 = false, f2 = false, f3 = false;
        int j = 4 * q;
        if (inb) {
            int4 p4 = prow4[q];
            f0 = (p4.x == c); f1 = (p4.y == c); f2 = (p4.z == c); f3 = (p4.w == c);
        }
        float4 a0, a1, a2, a3;           // early exec-masked gathers
        if (f0) a0 = arow[j + 0];
        if (f1) a1 = arow[j + 1];
        if (f2) a2 = arow[j + 2];
        if (f3) a3 = arow[j + 3];
        int cnt = (int)f0 + (int)f1 + (int)f2 + (int)f3;
        int incl = cnt;
#pragma unroll
        for (int d = 1; d < 64; d <<= 1) {
            int t = __shfl_up(incl, d, 64);
            if (lane >= d) incl += t;
        }
        int wtotal = __shfl(incl, 63, 64);
        int base = 0;
        if (lane == 63 && wtotal) base = atomicAdd(&s_acnt, wtotal);
        base = __shfl(base, 63, 64);
        int off = base + incl - cnt;
        if (f0) { if (off < ACACHE) { s_aidx[off] = j + 0; s_abox[off] = a0; } ++off; }
        if (f1) { if (off < ACACHE) { s_aidx[off] = j + 1; s_abox[off] = a1; } ++off; }
        if (f2) { if (off < ACACHE) { s_aidx[off] = j + 2; s_abox[off] = a2; } ++off; }
        if (f3) { if (off < ACACHE) { s_aidx[off] = j + 3; s_abox[off] = a3; } ++off; }
    }
    __syncthreads();
    int A_c = s_acnt;
    bool cached = (A_c <= ACACHE);

    // ---- 3. per-gt lex top-4; gts round-robin over waves; all state in
    //         scalar VGPRs; butterfly merge via static bitonic network ----
    for (int gi = wave; gi < G_c; gi += NWAVE) {
        float4 gb = gbox[gi];
        float v0 = -2.0f, v1 = -2.0f, v2 = -2.0f, v3 = -2.0f;  // sentinel < any IoU
        int   j0 = INT_MAX, j1 = INT_MAX, j2 = INT_MAX, j3 = INT_MAX;
        if (cached) {
            for (int slot = lane; slot < A_c; slot += 64) {
                float4 ab = s_abox[slot];
                int n = s_aidx[slot];
                float iou = iou_cxcywh(gb.x, gb.y, gb.z, gb.w, ab.x, ab.y, ab.z, ab.w);
                if (iou > v3 || (iou == v3 && n < j3)) {
                    v3 = iou; j3 = n;
                    CE(v2, j2, v3, j3); CE(v1, j1, v2, j2); CE(v0, j0, v1, j1);
                }
            }
        } else {  // cold: bucket overflowed LDS cache -> rescan globally
            for (int n = lane; n < NA; n += 64) {
                if (prompt[(size_t)b * NA + n] != c) continue;
                float4 ab = arow[n];
                float iou = iou_cxcywh(gb.x, gb.y, gb.z, gb.w, ab.x, ab.y, ab.z, ab.w);
                if (iou > v3 || (iou == v3 && n < j3)) {
                    v3 = iou; j3 = n;
                    CE(v2, j2, v3, j3); CE(v1, j1, v2, j2); CE(v0, j0, v1, j1);
                }
            }
        }
        // butterfly: both lists sorted desc; [v0..v3, w3..w0] is bitonic.
#pragma unroll
        for (int mask = 1; mask < 64; mask <<= 1) {
            float w0 = __shfl_xor(v0, mask, 64), w1 = __shfl_xor(v1, mask, 64);
            float w2 = __shfl_xor(v2, mask, 64), w3 = __shfl_xor(v3, mask, 64);
            int   k0 = __shfl_xor(j0, mask, 64), k1 = __shfl_xor(j1, mask, 64);
            int   k2 = __shfl_xor(j2, mask, 64), k3 = __shfl_xor(j3, mask, 64);
            CE(v0, j0, w3, k3); CE(v1, j1, w2, k2);      // stage 1: top half
            CE(v2, j2, w1, k1); CE(v3, j3, w0, k0);
            CE(v0, j0, v2, j2); CE(v1, j1, v3, j3);      // bitonic-4 cleanup
            CE(v0, j0, v1, j1); CE(v2, j2, v3, j3);
        }
        if (lane == 0) {
            gmaxv[gi] = v0;
            gtv[gi*KK+0] = v0; gti[gi*KK+0] = j0;
            gtv[gi*KK+1] = v1; gti[gi*KK+1] = j1;
            gtv[gi*KK+2] = v2; gti[gi*KK+2] = j2;
            gtv[gi*KK+3] = v3; gti[gi*KK+3] = j3;
        }
    }
    __syncthreads();

    // ---- 4. per-anchor: argmax (first occurrence: ascending gi, strict >),
    //         lq (iou == gt row max, exact), pos, per-gt counts ----
    if (cached) {
        for (int slot = tid; slot < A_c; slot += BLK) {
            float4 ab = s_abox[slot];
            float amax = -1.0f; int aarg = 0; bool lq = false;
            for (int gi = 0; gi < G_c; ++gi) {
                float4 gb = gbox[gi];
                float iou = iou_cxcywh(gb.x, gb.y, gb.z, gb.w, ab.x, ab.y, ab.z, ab.w);
                lq = lq || (iou == gmaxv[gi]);
                if (iou > amax) { amax = iou; aarg = gi; }
            }
            u.aarg[slot] = (unsigned short)aarg;
            if (lq || amax >= T_HIGH) {
                atomicOr(&s_posbit[slot >> 5], 1u << (slot & 31));
                atomicAdd(&lcount[aarg], 1);
                atomicAdd(&s_ptotal, 1);
            }
        }
    } else {  // cold: bitmask indexed by global anchor index
        for (int n = tid; n < NA; n += BLK) {
            if (prompt[(size_t)b * NA + n] != c) continue;
            float4 ab = arow[n];
            float amax = -1.0f; int aarg = 0; bool lq = false;
            for (int gi = 0; gi < G_c; ++gi) {
                float4 gb = gbox[gi];
                float iou = iou_cxcywh(gb.x, gb.y, gb.z, gb.w, ab.x, ab.y, ab.z, ab.w);
                lq = lq || (iou == gmaxv[gi]);
                if (iou > amax) { amax = iou; aarg = gi; }
            }
            if (lq || amax >= T_HIGH) {
                atomicOr(&s_posbit[n >> 5], 1u << (n & 31));
                atomicAdd(&lcount[aarg], 1);
                atomicAdd(&s_ptotal, 1);
            }
        }
    }
    __syncthreads();
    int ptotal = s_ptotal;

    // ---- 5. subsample: > MAXPOS positives -> keep first MAXPOS by anchor
    //         index (exact stable argsort-by-(class,idx) rank) ----
    if (ptotal > MAXPOS) {
        for (int gi = tid; gi < G_c; gi += BLK) lcount[gi] = 0;
        __syncthreads();
        if (cached) {
            for (int slot = tid; slot < A_c; slot += BLK) {
                if (!((s_posbit[slot >> 5] >> (slot & 31)) & 1)) continue;
                int n = s_aidx[slot];
                int rank = 0;
                for (int s2 = 0; s2 < A_c; ++s2)
                    if (((s_posbit[s2 >> 5] >> (s2 & 31)) & 1) && s_aidx[s2] < n) ++rank;
                if (rank < MAXPOS) atomicAdd(&lcount[u.aarg[slot]], 1);
            }
        } else {  // cold^2: ordered block scan over the n-indexed bitmask
            int running = 0;
            for (int base = 0; base < NA && running < MAXPOS; base += BLK) {
                int n = base + tid;
                int flag = (n < NA) && ((s_posbit[n >> 5] >> (n & 31)) & 1);
                u.sd[tid] = flag;
                __syncthreads();
                for (int off = 1; off < BLK; off <<= 1) {
                    int v = (tid >= off) ? u.sd[tid - off] : 0;
                    __syncthreads();
                    u.sd[tid] += v;
                    __syncthreads();
                }
                int rank = running + u.sd[tid] - flag;
                int total = u.sd[BLK - 1];
                if (flag && rank < MAXPOS) {
                    float4 ab = arow[n];
                    float amax = -1.0f; int aarg = 0;
                    for (int gi = 0; gi < G_c; ++gi) {
                        float4 gb = gbox[gi];
                        float iou = iou_cxcywh(gb.x, gb.y, gb.z, gb.w, ab.x, ab.y, ab.z, ab.w);
                        if (iou > amax) { amax = iou; aarg = gi; }
                    }
                    atomicAdd(&lcount[aarg], 1);
                }
                running += total;
                __syncthreads();
            }
        }
        __syncthreads();
    }

    // ---- 6. outputs for this class's gts: [4][B,G,K] concatenated ----
    const int TOT = BB * GG * KK;
    for (int t = tid; t < G_c * KK; t += BLK) {
        int gi = t >> 2, k = t & 3;
        int gg = gidx[gi];
        int cnt = lcount[gi]; if (cnt > KK) cnt = KK;
        bool svld = (k < cnt);
        int o = (b * GG + gg) * KK + k;
        out[o]           = svld ? (float)gti[t] : -1.0f;   // pr_inds
        out[TOT + o]     = svld ? (float)gg     : -1.0f;   // gt_inds
        out[2*TOT + o]   = svld ? 1.0f : 0.0f;             // slot_valid
        out[3*TOT + o]   = svld ? gtv[t] : 0.0f;           // pos_iou
    }
}

extern "C" void kernel_launch(void* const* d_in, const int* in_sizes, int n_in,
                              void* d_out, int out_size, void* d_ws, size_t ws_size,
                              hipStream_t stream) {
    // inputs: 0 pred_logits_match (unused), 1 pred_boxes (unused),
    //         2 anchors, 3 prompt_inds, 4 tgt_labels, 5 tgt_boxes
    const float* anchors = (const float*)d_in[2];
    const int*   prompt  = (const int*)d_in[3];
    const int*   tlabels = (const int*)d_in[4];
    const float* tboxes  = (const float*)d_in[5];
    float* out = (float*)d_out;

    k_main<<<BB * NCLS, BLK, 0, stream>>>(anchors, prompt, tlabels, tboxes, out);
}